// Round 1
// baseline (178.678 us; speedup 1.0000x reference)
//
#include <hip/hip_runtime.h>
#include <cstddef>

// Problem constants (match reference)
constexpr int T_ = 8;        // tables
constexpr int N_ = 500000;   // rows per table
constexpr int D_ = 64;       // embedding dim (== wavefront size!)
constexpr int B_ = 16384;    // batch
constexpr int L_ = 20;       // bag length
constexpr int F_ = 256;      // dense float dim
constexpr int K_ = 10;       // dense projection dim

// ---------------------------------------------------------------------------
// Kernel 1: fold W_dense @ W_over[512:522] into a single 256-vector w_eff,
// and all biases into one scalar.  w_eff layout in ws: [256 floats][1 float bias]
// ---------------------------------------------------------------------------
__global__ __launch_bounds__(256) void prep_weights(
    const float* __restrict__ W_dense,   // [F,10]
    const float* __restrict__ b_dense,   // [10]
    const float* __restrict__ W_over,    // [522,1]
    const float* __restrict__ b_over,    // [1]
    float* __restrict__ w_eff)           // ws: 257 floats
{
    const int f = threadIdx.x;           // 0..255
    float acc = 0.f;
#pragma unroll
    for (int k = 0; k < K_; ++k)
        acc = fmaf(W_dense[f * K_ + k], W_over[T_ * D_ + k], acc);
    w_eff[f] = acc;
    if (f == 0) {
        float bb = b_over[0];
#pragma unroll
        for (int k = 0; k < K_; ++k)
            bb = fmaf(b_dense[k], W_over[T_ * D_ + k], bb);
        w_eff[F_] = bb;
    }
}

// ---------------------------------------------------------------------------
// Kernel 2: one wave per sample b.  Lane d handles element d of every
// gathered 64-float row -> each gather = one coalesced 256B request/wave.
// Accumulate row·W_over_slice directly (pooled never materialized), add the
// folded dense contribution, wave-reduce, sigmoid, store pred[b].
// ---------------------------------------------------------------------------
__global__ __launch_bounds__(256) void fused_retrieval(
    const int*   __restrict__ indices,   // [B,T,L]
    const float* __restrict__ dense,     // [B,F]
    const float* __restrict__ tables,    // [T,N,D]
    const float* __restrict__ W_over,    // [522]
    const float* __restrict__ w_eff,     // [257] from prep
    float*       __restrict__ out)       // out[0]=sum (later), out[1..B]=pred
{
    const int lane = threadIdx.x & 63;
    const int wid  = threadIdx.x >> 6;       // 4 waves / block
    const int b    = (blockIdx.x << 2) + wid;

    const int* __restrict__ idx = indices + (size_t)b * (T_ * L_);

    float acc = 0.f;
#pragma unroll
    for (int t = 0; t < T_; ++t) {
        const float w = W_over[t * D_ + lane];          // cached, 256B/wave
        const float* __restrict__ tab = tables + (size_t)t * N_ * D_;
        int ix[L_];
#pragma unroll
        for (int l = 0; l < L_; ++l) ix[l] = idx[t * L_ + l];  // uniform, L1-hit
#pragma unroll
        for (int l = 0; l < L_; ++l)
            acc = fmaf(tab[(size_t)ix[l] * D_ + lane], w, acc);
    }

    // Dense contribution: lane owns 4 consecutive f's -> float4 coalesced.
    const float4 dv = *reinterpret_cast<const float4*>(dense + (size_t)b * F_ + lane * 4);
    const float4 wv = *reinterpret_cast<const float4*>(w_eff + lane * 4);
    acc = fmaf(dv.x, wv.x, acc);
    acc = fmaf(dv.y, wv.y, acc);
    acc = fmaf(dv.z, wv.z, acc);
    acc = fmaf(dv.w, wv.w, acc);

    // 64-lane butterfly reduce
#pragma unroll
    for (int off = 32; off > 0; off >>= 1)
        acc += __shfl_xor(acc, off, 64);

    if (lane == 0) {
        const float logit = acc + w_eff[F_];
        out[1 + b] = 1.f / (1.f + expf(-logit));
    }
}

// ---------------------------------------------------------------------------
// Kernel 3: deterministic single-block sum of pred -> out[0].
// (No float atomics: bit-stable across graph replays.)
// ---------------------------------------------------------------------------
__global__ __launch_bounds__(1024) void reduce_sum(
    const float* __restrict__ pred,      // out+1, B_ floats (4B-offset, scalar loads)
    float* __restrict__ out0)
{
    float acc = 0.f;
    for (int i = threadIdx.x; i < B_; i += 1024)
        acc += pred[i];
#pragma unroll
    for (int off = 32; off > 0; off >>= 1)
        acc += __shfl_xor(acc, off, 64);
    __shared__ float sm[16];
    if ((threadIdx.x & 63) == 0) sm[threadIdx.x >> 6] = acc;
    __syncthreads();
    if (threadIdx.x == 0) {
        float s = 0.f;
#pragma unroll
        for (int w = 0; w < 16; ++w) s += sm[w];
        out0[0] = s;
    }
}

extern "C" void kernel_launch(void* const* d_in, const int* in_sizes, int n_in,
                              void* d_out, int out_size, void* d_ws, size_t ws_size,
                              hipStream_t stream) {
    const int*   indices = (const int*)  d_in[0];
    const float* dense   = (const float*)d_in[1];
    const float* tables  = (const float*)d_in[2];
    const float* W_dense = (const float*)d_in[3];
    const float* b_dense = (const float*)d_in[4];
    const float* W_over  = (const float*)d_in[5];
    const float* b_over  = (const float*)d_in[6];
    float* out   = (float*)d_out;   // [0]=sum, [1..B]=pred
    float* w_eff = (float*)d_ws;    // 257 floats of scratch

    prep_weights<<<1, 256, 0, stream>>>(W_dense, b_dense, W_over, b_over, w_eff);
    fused_retrieval<<<B_ / 4, 256, 0, stream>>>(indices, dense, tables, W_over, w_eff, out);
    reduce_sum<<<1, 1024, 0, stream>>>(out + 1, out);
}

// Round 2
// 116.908 us; speedup vs baseline: 1.5284x; 1.5284x over previous
//
#include <hip/hip_runtime.h>
#include <cstddef>

// Problem constants (match reference)
constexpr int T_ = 8;        // tables
constexpr int N_ = 500000;   // rows per table
constexpr int D_ = 64;       // embedding dim (== wavefront size)
constexpr int B_ = 16384;    // batch
constexpr int L_ = 20;       // bag length
constexpr int F_ = 256;      // dense float dim
constexpr int K_ = 10;       // dense projection dim

// ---------------------------------------------------------------------------
// Kernel 1: fold W_dense @ W_over[512:522] into a single 256-vector w_eff,
// and all biases into one scalar.  ws layout: [256 floats w_eff][1 float bias]
// ---------------------------------------------------------------------------
__global__ __launch_bounds__(256) void prep_weights(
    const float* __restrict__ W_dense,   // [F,10]
    const float* __restrict__ b_dense,   // [10]
    const float* __restrict__ W_over,    // [522,1]
    const float* __restrict__ b_over,    // [1]
    float* __restrict__ w_eff)           // ws: 257 floats
{
    const int f = threadIdx.x;           // 0..255
    float acc = 0.f;
#pragma unroll
    for (int k = 0; k < K_; ++k)
        acc = fmaf(W_dense[f * K_ + k], W_over[T_ * D_ + k], acc);
    w_eff[f] = acc;
    if (f == 0) {
        float bb = b_over[0];
#pragma unroll
        for (int k = 0; k < K_; ++k)
            bb = fmaf(b_dense[k], W_over[T_ * D_ + k], bb);
        w_eff[F_] = bb;
    }
}

// ---------------------------------------------------------------------------
// Kernel 2: one wave per sample b.  b forced into SGPR (readfirstlane) so the
// 160 wave-uniform index loads become s_load (scalar path, SGPRs) and gather
// addresses are SGPR-base + lane*4.  2-stage index pipeline: scalar-load
// table t+1's indices while table t's 20 gathers are in flight.  4 rotating
// accumulators break the fma dependency chain.
// ---------------------------------------------------------------------------
__global__ __launch_bounds__(256) void fused_retrieval(
    const int*   __restrict__ indices,   // [B,T,L]
    const float* __restrict__ dense,     // [B,F]
    const float* __restrict__ tables,    // [T,N,D]
    const float* __restrict__ W_over,    // [522]
    const float* __restrict__ w_eff,     // [257] from prep
    float*       __restrict__ out)       // out[0]=sum (later), out[1..B]=pred
{
    const int lane = threadIdx.x & 63;
    const int wid  = threadIdx.x >> 6;                       // 4 waves / block
    const int b    = __builtin_amdgcn_readfirstlane((blockIdx.x << 2) + wid);

    const int* __restrict__ idx = indices + (size_t)b * (T_ * L_);

    // Per-table W_over slices: 8 coalesced 256B loads, kept in VGPRs.
    float w[T_];
#pragma unroll
    for (int t = 0; t < T_; ++t) w[t] = W_over[t * D_ + lane];

    // Independent dense prefetch (float4, coalesced).
    const float4 dv = *reinterpret_cast<const float4*>(dense + (size_t)b * F_ + lane * 4);
    const float4 wv = *reinterpret_cast<const float4*>(w_eff + lane * 4);

    float a0 = 0.f, a1 = 0.f, a2 = 0.f, a3 = 0.f;

    int ixc[L_], ixn[L_];
#pragma unroll
    for (int l = 0; l < L_; ++l) ixc[l] = idx[l];            // t=0 indices (s_load)

#pragma unroll
    for (int t = 0; t < T_; ++t) {
        // Prefetch next table's indices (scalar loads overlap the gathers).
        if (t + 1 < T_) {
#pragma unroll
            for (int l = 0; l < L_; ++l) ixn[l] = idx[(t + 1) * L_ + l];
        }
        const float* __restrict__ tab = tables + (size_t)t * N_ * D_;
        const float wt = w[t];
#pragma unroll
        for (int l = 0; l < L_; ++l) {
            const float v = tab[(size_t)ixc[l] * D_ + lane]; // 256B/wave gather
            if      ((l & 3) == 0) a0 = fmaf(v, wt, a0);
            else if ((l & 3) == 1) a1 = fmaf(v, wt, a1);
            else if ((l & 3) == 2) a2 = fmaf(v, wt, a2);
            else                   a3 = fmaf(v, wt, a3);
        }
#pragma unroll
        for (int l = 0; l < L_; ++l) ixc[l] = ixn[l];
    }

    float acc = (a0 + a1) + (a2 + a3);
    acc = fmaf(dv.x, wv.x, acc);
    acc = fmaf(dv.y, wv.y, acc);
    acc = fmaf(dv.z, wv.z, acc);
    acc = fmaf(dv.w, wv.w, acc);

    // 64-lane butterfly reduce
#pragma unroll
    for (int off = 32; off > 0; off >>= 1)
        acc += __shfl_xor(acc, off, 64);

    if (lane == 0) {
        const float logit = acc + w_eff[F_];
        out[1 + b] = 1.f / (1.f + expf(-logit));
    }
}

// ---------------------------------------------------------------------------
// Kernel 3: deterministic single-block sum of pred -> out[0].
// ---------------------------------------------------------------------------
__global__ __launch_bounds__(1024) void reduce_sum(
    const float* __restrict__ pred,      // out+1, B_ floats
    float* __restrict__ out0)
{
    float acc = 0.f;
    for (int i = threadIdx.x; i < B_; i += 1024)
        acc += pred[i];
#pragma unroll
    for (int off = 32; off > 0; off >>= 1)
        acc += __shfl_xor(acc, off, 64);
    __shared__ float sm[16];
    if ((threadIdx.x & 63) == 0) sm[threadIdx.x >> 6] = acc;
    __syncthreads();
    if (threadIdx.x == 0) {
        float s = 0.f;
#pragma unroll
        for (int w = 0; w < 16; ++w) s += sm[w];
        out0[0] = s;
    }
}

extern "C" void kernel_launch(void* const* d_in, const int* in_sizes, int n_in,
                              void* d_out, int out_size, void* d_ws, size_t ws_size,
                              hipStream_t stream) {
    const int*   indices = (const int*)  d_in[0];
    const float* dense   = (const float*)d_in[1];
    const float* tables  = (const float*)d_in[2];
    const float* W_dense = (const float*)d_in[3];
    const float* b_dense = (const float*)d_in[4];
    const float* W_over  = (const float*)d_in[5];
    const float* b_over  = (const float*)d_in[6];
    float* out   = (float*)d_out;   // [0]=sum, [1..B]=pred
    float* w_eff = (float*)d_ws;    // 257 floats of scratch

    prep_weights<<<1, 256, 0, stream>>>(W_dense, b_dense, W_over, b_over, w_eff);
    fused_retrieval<<<B_ / 4, 256, 0, stream>>>(indices, dense, tables, W_over, w_eff, out);
    reduce_sum<<<1, 1024, 0, stream>>>(out + 1, out);
}

// Round 4
// 113.835 us; speedup vs baseline: 1.5696x; 1.0270x over previous
//
#include <hip/hip_runtime.h>
#include <cstddef>

// Problem constants (match reference)
constexpr int T_ = 8;        // tables
constexpr int N_ = 500000;   // rows per table
constexpr int D_ = 64;       // embedding dim (== wavefront size)
constexpr int B_ = 16384;    // batch
constexpr int L_ = 20;       // bag length
constexpr int F_ = 256;      // dense float dim
constexpr int K_ = 10;       // dense projection dim
constexpr int NBLK_ = B_ / 4;  // 4096 fused blocks (4 samples each)

// ws layout: [0..255] w_eff, [256] folded bias, [257..] per-block partial sums
// ---------------------------------------------------------------------------
// Kernel 1: fold W_dense @ W_over[512:522] into w_eff[256], biases into ws[256].
// ---------------------------------------------------------------------------
__global__ __launch_bounds__(256) void prep_weights(
    const float* __restrict__ W_dense,   // [F,10]
    const float* __restrict__ b_dense,   // [10]
    const float* __restrict__ W_over,    // [522,1]
    const float* __restrict__ b_over,    // [1]
    float* __restrict__ w_eff)           // ws
{
    const int f = threadIdx.x;           // 0..255
    float acc = 0.f;
#pragma unroll
    for (int k = 0; k < K_; ++k)
        acc = fmaf(W_dense[f * K_ + k], W_over[T_ * D_ + k], acc);
    w_eff[f] = acc;
    if (f == 0) {
        float bb = b_over[0];
#pragma unroll
        for (int k = 0; k < K_; ++k)
            bb = fmaf(b_dense[k], W_over[T_ * D_ + k], bb);
        w_eff[F_] = bb;
    }
}

// ---------------------------------------------------------------------------
// Kernel 2: one wave per sample.  SGPR sample id -> s_load indices, pipelined
// per-table: scalar-load t+1's indices while t's 20 gathers are in flight.
// Epilogue: pred[b] stored, and the block's 4 preds folded to one partial sum
// written to part[blockIdx.x] (separate non-const pointer).
// ---------------------------------------------------------------------------
__global__ __launch_bounds__(256) void fused_retrieval(
    const int*   __restrict__ indices,   // [B,T,L]
    const float* __restrict__ dense,     // [B,F]
    const float* __restrict__ tables,    // [T,N,D]
    const float* __restrict__ W_over,    // [522]
    const float* __restrict__ w_eff,     // ws (read-only here)
    float*       __restrict__ part,      // ws+257 (per-block partials)
    float*       __restrict__ out)       // out[0]=sum, out[1..B]=pred
{
    const int lane = threadIdx.x & 63;
    const int wid  = threadIdx.x >> 6;                       // 4 waves / block
    const int b    = __builtin_amdgcn_readfirstlane((blockIdx.x << 2) + wid);

    const int* __restrict__ idx = indices + (size_t)b * (T_ * L_);

    // Per-table W_over slices: 8 coalesced 256B loads, kept in VGPRs.
    float w[T_];
#pragma unroll
    for (int t = 0; t < T_; ++t) w[t] = W_over[t * D_ + lane];

    // Independent dense prefetch (float4, coalesced).
    const float4 dv = *reinterpret_cast<const float4*>(dense + (size_t)b * F_ + lane * 4);
    const float4 wv = *reinterpret_cast<const float4*>(w_eff + lane * 4);

    float a0 = 0.f, a1 = 0.f, a2 = 0.f, a3 = 0.f;

    int ixc[L_], ixn[L_];
#pragma unroll
    for (int l = 0; l < L_; ++l) ixc[l] = idx[l];            // t=0 indices (s_load)

#pragma unroll
    for (int t = 0; t < T_; ++t) {
        if (t + 1 < T_) {
#pragma unroll
            for (int l = 0; l < L_; ++l) ixn[l] = idx[(t + 1) * L_ + l];
        }
        const float* __restrict__ tab = tables + (size_t)t * N_ * D_;
        const float wt = w[t];
#pragma unroll
        for (int l = 0; l < L_; ++l) {
            const float v = tab[(size_t)ixc[l] * D_ + lane]; // 256B/wave gather
            if      ((l & 3) == 0) a0 = fmaf(v, wt, a0);
            else if ((l & 3) == 1) a1 = fmaf(v, wt, a1);
            else if ((l & 3) == 2) a2 = fmaf(v, wt, a2);
            else                   a3 = fmaf(v, wt, a3);
        }
#pragma unroll
        for (int l = 0; l < L_; ++l) ixc[l] = ixn[l];
    }

    float acc = (a0 + a1) + (a2 + a3);
    acc = fmaf(dv.x, wv.x, acc);
    acc = fmaf(dv.y, wv.y, acc);
    acc = fmaf(dv.z, wv.z, acc);
    acc = fmaf(dv.w, wv.w, acc);

#pragma unroll
    for (int off = 32; off > 0; off >>= 1)
        acc += __shfl_xor(acc, off, 64);

    __shared__ float sp[4];
    if (lane == 0) {
        const float logit = acc + w_eff[F_];
        const float pred  = 1.f / (1.f + expf(-logit));
        out[1 + b] = pred;
        sp[wid] = pred;
    }
    __syncthreads();
    if (threadIdx.x == 0)
        part[blockIdx.x] = (sp[0] + sp[1]) + (sp[2] + sp[3]);
}

// ---------------------------------------------------------------------------
// Kernel 3: deterministic single-block sum of 4096 block partials -> out[0].
// ---------------------------------------------------------------------------
__global__ __launch_bounds__(256) void reduce_sum(
    const float* __restrict__ part,      // ws+257, NBLK_ floats
    float* __restrict__ out0)
{
    float acc = 0.f;
#pragma unroll
    for (int i = 0; i < NBLK_ / 256; ++i)
        acc += part[i * 256 + threadIdx.x];
#pragma unroll
    for (int off = 32; off > 0; off >>= 1)
        acc += __shfl_xor(acc, off, 64);
    __shared__ float sm[4];
    if ((threadIdx.x & 63) == 0) sm[threadIdx.x >> 6] = acc;
    __syncthreads();
    if (threadIdx.x == 0)
        out0[0] = (sm[0] + sm[1]) + (sm[2] + sm[3]);
}

extern "C" void kernel_launch(void* const* d_in, const int* in_sizes, int n_in,
                              void* d_out, int out_size, void* d_ws, size_t ws_size,
                              hipStream_t stream) {
    const int*   indices = (const int*)  d_in[0];
    const float* dense   = (const float*)d_in[1];
    const float* tables  = (const float*)d_in[2];
    const float* W_dense = (const float*)d_in[3];
    const float* b_dense = (const float*)d_in[4];
    const float* W_over  = (const float*)d_in[5];
    const float* b_over  = (const float*)d_in[6];
    float* out   = (float*)d_out;   // [0]=sum, [1..B]=pred
    float* ws    = (float*)d_ws;    // [257 w_eff+bias][4096 partials]

    prep_weights<<<1, 256, 0, stream>>>(W_dense, b_dense, W_over, b_over, ws);
    fused_retrieval<<<NBLK_, 256, 0, stream>>>(indices, dense, tables, W_over, ws, ws + 257, out);
    reduce_sum<<<1, 256, 0, stream>>>(ws + 257, out);
}

// Round 5
// 113.353 us; speedup vs baseline: 1.5763x; 1.0043x over previous
//
#include <hip/hip_runtime.h>
#include <cstddef>

// Problem constants (match reference)
constexpr int T_ = 8;        // tables
constexpr int N_ = 500000;   // rows per table
constexpr int D_ = 64;       // embedding dim
constexpr int B_ = 16384;    // batch
constexpr int L_ = 20;       // bag length
constexpr int F_ = 256;      // dense float dim
constexpr int K_ = 10;       // dense projection dim
constexpr int NBLK_ = B_ / 4;  // 4096 fused blocks (4 samples each)

// ws layout: [0..255] w_eff, [256] folded bias, [257..] per-block partial sums
// ---------------------------------------------------------------------------
// Kernel 1: fold W_dense @ W_over[512:522] into w_eff[256], biases into ws[256].
// ---------------------------------------------------------------------------
__global__ __launch_bounds__(256) void prep_weights(
    const float* __restrict__ W_dense,   // [F,10]
    const float* __restrict__ b_dense,   // [10]
    const float* __restrict__ W_over,    // [522,1]
    const float* __restrict__ b_over,    // [1]
    float* __restrict__ w_eff)           // ws
{
    const int f = threadIdx.x;           // 0..255
    float acc = 0.f;
#pragma unroll
    for (int k = 0; k < K_; ++k)
        acc = fmaf(W_dense[f * K_ + k], W_over[T_ * D_ + k], acc);
    w_eff[f] = acc;
    if (f == 0) {
        float bb = b_over[0];
#pragma unroll
        for (int k = 0; k < K_; ++k)
            bb = fmaf(b_dense[k], W_over[T_ * D_ + k], bb);
        w_eff[F_] = bb;
    }
}

// ---------------------------------------------------------------------------
// Kernel 2: one wave per sample.  float4 gathers: 16 lanes per row, so one
// instruction fetches 4 rows -> 40 gather instrs/wave (was 160), 4x bytes in
// flight per vmcnt slot.  Lane (h=lane>>4, q=lane&15) accumulates bag
// elements l=4g+h over dims d=4q..4q+3; component-sum + butterfly recovers
// the full dot product.  Indices stay on the scalar path (SGPR, pipelined).
// ---------------------------------------------------------------------------
__global__ __launch_bounds__(256) void fused_retrieval(
    const int*   __restrict__ indices,   // [B,T,L]
    const float* __restrict__ dense,     // [B,F]
    const float* __restrict__ tables,    // [T,N,D]
    const float* __restrict__ W_over,    // [522]
    const float* __restrict__ w_eff,     // ws (read-only here)
    float*       __restrict__ part,      // ws+257 (per-block partials)
    float*       __restrict__ out)       // out[0]=sum, out[1..B]=pred
{
    const int lane = threadIdx.x & 63;
    const int wid  = threadIdx.x >> 6;                       // 4 waves / block
    const int b    = __builtin_amdgcn_readfirstlane((blockIdx.x << 2) + wid);
    const int h    = lane >> 4;                              // row group 0..3
    const int q    = lane & 15;                              // dim group 0..15

    const int* __restrict__ idx = indices + (size_t)b * (T_ * L_);

    // Per-table W_over float4 slices for this lane's d-range (broadcast in L1).
    float4 wq[T_];
#pragma unroll
    for (int t = 0; t < T_; ++t)
        wq[t] = *reinterpret_cast<const float4*>(W_over + t * D_ + q * 4);

    // Independent dense prefetch (float4, coalesced).
    const float4 dv = *reinterpret_cast<const float4*>(dense + (size_t)b * F_ + lane * 4);
    const float4 wv = *reinterpret_cast<const float4*>(w_eff + lane * 4);

    float4 acc0 = {0,0,0,0}, acc1 = {0,0,0,0}, acc2 = {0,0,0,0}, acc3 = {0,0,0,0};

    int ixc[L_], ixn[L_];
#pragma unroll
    for (int l = 0; l < L_; ++l) ixc[l] = idx[l];            // t=0 indices (s_load)

#pragma unroll
    for (int t = 0; t < T_; ++t) {
        if (t + 1 < T_) {
#pragma unroll
            for (int l = 0; l < L_; ++l) ixn[l] = idx[(t + 1) * L_ + l];
        }
        const float* __restrict__ tab = tables + (size_t)t * N_ * D_;
        const float4 wt = wq[t];
#pragma unroll
        for (int g = 0; g < L_ / 4; ++g) {                   // 5 gathers of 4 rows
            // explicit cndmask tree (no runtime-indexed array -> no scratch)
            const int r = (h == 0) ? ixc[4 * g + 0]
                        : (h == 1) ? ixc[4 * g + 1]
                        : (h == 2) ? ixc[4 * g + 2]
                        :            ixc[4 * g + 3];
            const float4 v = *reinterpret_cast<const float4*>(tab + (size_t)r * D_ + q * 4);
            float4& a = (g & 3) == 0 ? acc0 : (g & 3) == 1 ? acc1 : (g & 3) == 2 ? acc2 : acc3;
            a.x = fmaf(v.x, wt.x, a.x);
            a.y = fmaf(v.y, wt.y, a.y);
            a.z = fmaf(v.z, wt.z, a.z);
            a.w = fmaf(v.w, wt.w, a.w);
        }
#pragma unroll
        for (int l = 0; l < L_; ++l) ixc[l] = ixn[l];
    }

    float acc = ((acc0.x + acc0.y) + (acc0.z + acc0.w))
              + ((acc1.x + acc1.y) + (acc1.z + acc1.w))
              + ((acc2.x + acc2.y) + (acc2.z + acc2.w))
              + ((acc3.x + acc3.y) + (acc3.z + acc3.w));
    acc = fmaf(dv.x, wv.x, acc);
    acc = fmaf(dv.y, wv.y, acc);
    acc = fmaf(dv.z, wv.z, acc);
    acc = fmaf(dv.w, wv.w, acc);

#pragma unroll
    for (int off = 32; off > 0; off >>= 1)
        acc += __shfl_xor(acc, off, 64);

    __shared__ float sp[4];
    if (lane == 0) {
        const float logit = acc + w_eff[F_];
        const float pred  = 1.f / (1.f + expf(-logit));
        out[1 + b] = pred;
        sp[wid] = pred;
    }
    __syncthreads();
    if (threadIdx.x == 0)
        part[blockIdx.x] = (sp[0] + sp[1]) + (sp[2] + sp[3]);
}

// ---------------------------------------------------------------------------
// Kernel 3: deterministic single-block sum of 4096 block partials -> out[0].
// ---------------------------------------------------------------------------
__global__ __launch_bounds__(256) void reduce_sum(
    const float* __restrict__ part,      // ws+257, NBLK_ floats
    float* __restrict__ out0)
{
    float acc = 0.f;
#pragma unroll
    for (int i = 0; i < NBLK_ / 256; ++i)
        acc += part[i * 256 + threadIdx.x];
#pragma unroll
    for (int off = 32; off > 0; off >>= 1)
        acc += __shfl_xor(acc, off, 64);
    __shared__ float sm[4];
    if ((threadIdx.x & 63) == 0) sm[threadIdx.x >> 6] = acc;
    __syncthreads();
    if (threadIdx.x == 0)
        out0[0] = (sm[0] + sm[1]) + (sm[2] + sm[3]);
}

extern "C" void kernel_launch(void* const* d_in, const int* in_sizes, int n_in,
                              void* d_out, int out_size, void* d_ws, size_t ws_size,
                              hipStream_t stream) {
    const int*   indices = (const int*)  d_in[0];
    const float* dense   = (const float*)d_in[1];
    const float* tables  = (const float*)d_in[2];
    const float* W_dense = (const float*)d_in[3];
    const float* b_dense = (const float*)d_in[4];
    const float* W_over  = (const float*)d_in[5];
    const float* b_over  = (const float*)d_in[6];
    float* out   = (float*)d_out;   // [0]=sum, [1..B]=pred
    float* ws    = (float*)d_ws;    // [257 w_eff+bias][4096 partials]

    prep_weights<<<1, 256, 0, stream>>>(W_dense, b_dense, W_over, b_over, ws);
    fused_retrieval<<<NBLK_, 256, 0, stream>>>(indices, dense, tables, W_over, ws, ws + 257, out);
    reduce_sum<<<1, 256, 0, stream>>>(ws + 257, out);
}